// Round 1
// baseline (196.188 us; speedup 1.0000x reference)
//
#include <hip/hip_runtime.h>

// ---------------- problem constants ----------------
// B*P=32, N=512, D=128, H=4, DK=32, T=3 (tm {0,1,3}; tsel(t)=t+(t>>1))
// Inputs f32, OUTPUT f32. XL path (ws >= 54.9MB) confirmed.
// R13: 171.5us; k_attn2 ~57us, MfmaUtil 8.6 / VALUBusy 36 / HBM 11% -> issue-
// latency bound on the P-loop (scalar tm loads + scalar b16 P stores + 3-op za).
// R14: transpose QK^T (mfma(kf,qf) -> S^T, lane holds 4 consecutive m):
//   tm loads 16x dword -> 4x dwordx4 (imm-folded offsets), P store 16x b16 ->
//   4x b64 via v_cvt_pk_bf16_f32, za scalar-per-strip with ceil() indicator,
//   epilogue 16 shuffles -> 2 xor + 4 bpermute. PV path unchanged.

typedef __attribute__((ext_vector_type(8))) short  short8;
typedef __attribute__((ext_vector_type(4))) float  floatx4;
typedef __attribute__((ext_vector_type(2))) unsigned int uint2v;

#define WS_BIG   50331648ull                  // q3/k3/v3 (37.7MB) + att (12.6MB)
#define WS_XL    54919168ull                  // + Xb 4MB + Wb 288KB + Wob 96KB
#define QSCALE   0.25503486f                  // (1/sqrt(32)) * log2(e)

__device__ __forceinline__ float b2f(unsigned short u) {
    union { unsigned int i; float f; } v; v.i = ((unsigned int)u) << 16; return v.f;
}
__device__ __forceinline__ unsigned short f2b(float f) {
    union { float f; unsigned int i; } v; v.f = f;
    unsigned int x = v.i;
    return (unsigned short)((x + 0x7fffu + ((x >> 16) & 1u)) >> 16);
}
__device__ __forceinline__ unsigned int cvt_pk_bf16(float a, float b) {
    unsigned int r;
    asm("v_cvt_pk_bf16_f32 %0, %1, %2" : "=v"(r) : "v"(a), "v"(b));
    return r;
}
__device__ __forceinline__ short8 cvt8(const float* p) {
    floatx4 a = *(const floatx4*)p;
    floatx4 b = *(const floatx4*)(p + 4);
    short8 r;
    r[0] = (short)f2b(a[0]); r[1] = (short)f2b(a[1]);
    r[2] = (short)f2b(a[2]); r[3] = (short)f2b(a[3]);
    r[4] = (short)f2b(b[0]); r[5] = (short)f2b(b[1]);
    r[6] = (short)f2b(b[2]); r[7] = (short)f2b(b[3]);
    return r;
}

// ---------------- K0: one-time f32->bf16 conversion of X, Wq/Wk/Wv, Wo --------
__global__ __launch_bounds__(256) void k_prep(
    const float* __restrict__ X,  const float* __restrict__ Wq,
    const float* __restrict__ Wk, const float* __restrict__ Wv,
    const float* __restrict__ Wo,
    unsigned short* __restrict__ Xb, unsigned short* __restrict__ Wb,
    unsigned short* __restrict__ Wob)
{
    size_t i = ((size_t)blockIdx.x * 256 + threadIdx.x) * 8;
    const float* src; unsigned short* dst; size_t off;
    if      (i < 2097152) { src = X;  dst = Xb;          off = i; }
    else if (i < 2146304) { src = Wq; dst = Wb;          off = i - 2097152; }
    else if (i < 2195456) { src = Wk; dst = Wb + 49152;  off = i - 2146304; }
    else if (i < 2244608) { src = Wv; dst = Wb + 98304;  off = i - 2195456; }
    else                  { src = Wo; dst = Wob;         off = i - 2244608; }
    *(short8*)&dst[off] = cvt8(&src[off]);
}

// ---------------- K1a: QKV projection (R12-proven, LDS-repacked stores) -------
__global__ __launch_bounds__(256) void k_qkv_pre(
    const unsigned short* __restrict__ Xb,   // [32][512][128] bf16
    const unsigned short* __restrict__ Wb,   // [3 qkv][3 t][128][128] bf16
    unsigned short* __restrict__ q_ws,
    unsigned short* __restrict__ k_ws,
    unsigned short* __restrict__ v_ws)
{
    int bp = blockIdx.x, mt = blockIdx.y, tz = blockIdx.z;
    __shared__ unsigned short Xs[128 * 128];     // 32 KB
    __shared__ unsigned short Cs[4][32 * 128];   // 32 KB (8KB per wave)
    int tid = threadIdx.x;
    int lane = tid & 63, wv = tid >> 6;
    int l15 = lane & 15, quad = lane >> 4;

    const unsigned short* Xbase = Xb + ((size_t)bp * 512 + mt * 128) * 128;
    for (int i = 0; i < 8; ++i) {
        int e = (i * 256 + tid) * 8;
        *(short8*)&Xs[e] = *(const short8*)&Xbase[e];
    }
    __syncthreads();

    unsigned short* Osel[3] = { q_ws, k_ws, v_ws };
    int rt0 = wv * 2, rt1 = wv * 2 + 1;

    for (int qkv = 0; qkv < 3; ++qkv) {
        const unsigned short* Wt = Wb + qkv * 49152 + tz * 16384;
        unsigned short* Ob = Osel[qkv] + (size_t)tz * 2097152
                           + ((size_t)bp * 512 + mt * 128 + wv * 32) * 128;
        float sc = (qkv == 0) ? QSCALE : 1.0f;

        for (int ct = 0; ct < 8; ++ct) {
            short8 bfr[4];
            for (int kk = 0; kk < 4; ++kk)
                bfr[kk] = *(const short8*)&Wt[(size_t)(ct * 16 + l15) * 128 + kk * 32 + quad * 8];
            floatx4 acc0 = {0.f, 0.f, 0.f, 0.f};
            floatx4 acc1 = {0.f, 0.f, 0.f, 0.f};
            for (int kk = 0; kk < 4; ++kk) {
                short8 a0 = *(const short8*)&Xs[(rt0 * 16 + l15) * 128 + kk * 32 + quad * 8];
                short8 a1 = *(const short8*)&Xs[(rt1 * 16 + l15) * 128 + kk * 32 + quad * 8];
                acc0 = __builtin_amdgcn_mfma_f32_16x16x32_bf16(a0, bfr[kk], acc0, 0, 0, 0);
                acc1 = __builtin_amdgcn_mfma_f32_16x16x32_bf16(a1, bfr[kk], acc1, 0, 0, 0);
            }
            #pragma unroll
            for (int i = 0; i < 4; ++i) {
                int row = quad * 4 + i;
                int swz = (row & 7) << 4;
                int col = (ct * 16 + l15) ^ swz;
                Cs[wv][row * 128 + col]        = f2b(acc0[i] * sc);
                Cs[wv][(16 + row) * 128 + col] = f2b(acc1[i] * sc);
            }
        }
        #pragma unroll
        for (int j = 0; j < 8; ++j) {
            int flat = j * 64 + lane;
            int r = flat >> 4;
            int cg = (flat & 15) * 8;
            int cgs = cg ^ ((r & 7) << 4);
            *(short8*)&Ob[(size_t)r * 128 + cg] = *(const short8*)&Cs[wv][r * 128 + cgs];
        }
    }
}

// ---------------- K1b: QKV projection, inline-cvt fallback --------------------
__global__ __launch_bounds__(256) void k_qkv_cvt(
    const float* __restrict__ X,
    const float* __restrict__ Wq, const float* __restrict__ Wk,
    const float* __restrict__ Wv,
    unsigned short* __restrict__ q_ws, unsigned short* __restrict__ k_ws,
    unsigned short* __restrict__ v_ws,
    int wstride, int ostride)
{
    int bp = blockIdx.x, mt = blockIdx.y, tz = blockIdx.z;
    __shared__ unsigned short Xs[128 * 128];
    int tid = threadIdx.x;
    int lane = tid & 63, wv = tid >> 6;
    int l15 = lane & 15, quad = lane >> 4;

    const float* Xbase = X + ((size_t)bp * 512 + mt * 128) * 128;
    for (int i = 0; i < 8; ++i) {
        int e = (i * 256 + tid) * 8;
        *(short8*)&Xs[e] = cvt8(&Xbase[e]);
    }
    __syncthreads();

    size_t woff = (size_t)tz * wstride;
    size_t ooff = (size_t)tz * ostride;
    const float* Wsel[3] = { Wq + woff, Wk + woff, Wv + woff };
    unsigned short* Osel[3] = { q_ws + ooff, k_ws + ooff, v_ws + ooff };

    for (int qkv = 0; qkv < 3; ++qkv) {
        const float* Wt = Wsel[qkv];
        unsigned short* Ob = Osel[qkv] + ((size_t)bp * 512 + mt * 128) * 128;
        float sc = (qkv == 0) ? QSCALE : 1.0f;
        for (int ct = 0; ct < 8; ++ct) {
            short8 bfr[4];
            for (int kk = 0; kk < 4; ++kk)
                bfr[kk] = cvt8(&Wt[(size_t)(ct * 16 + l15) * 128 + kk * 32 + quad * 8]);
            floatx4 acc0 = {0.f, 0.f, 0.f, 0.f};
            floatx4 acc1 = {0.f, 0.f, 0.f, 0.f};
            int rt0 = wv * 2, rt1 = wv * 2 + 1;
            for (int kk = 0; kk < 4; ++kk) {
                short8 a0 = *(const short8*)&Xs[(rt0 * 16 + l15) * 128 + kk * 32 + quad * 8];
                short8 a1 = *(const short8*)&Xs[(rt1 * 16 + l15) * 128 + kk * 32 + quad * 8];
                acc0 = __builtin_amdgcn_mfma_f32_16x16x32_bf16(a0, bfr[kk], acc0, 0, 0, 0);
                acc1 = __builtin_amdgcn_mfma_f32_16x16x32_bf16(a1, bfr[kk], acc1, 0, 0, 0);
            }
            int col = ct * 16 + l15;
            for (int i = 0; i < 4; ++i) {
                Ob[(size_t)(rt0 * 16 + quad * 4 + i) * 128 + col] = f2b(acc0[i] * sc);
                Ob[(size_t)(rt1 * 16 + quad * 4 + i) * 128 + col] = f2b(acc1[i] * sc);
            }
        }
    }
}

// ---------------- K2: dense MFMA attention, transposed-S P-loop (R14) ---------
// grid (nc2=2, bp=32, z=t*4+h) = 768 blocks = exactly 3/CU (52KB LDS allows 3).
// Wave wv handles strips n0 = nc2*256 + wv*16 and n0+128 against each staged
// K chunk. S^T = mfma(kf, qf): lane (quad,l15) holds m = mb+ti*16+quad*4+i,
// n = ns+l15 -> tm as dwordx4/lane, P store as b64 (2x cvt_pk), za scalar.
__global__ __launch_bounds__(512) void k_attn3(
    const unsigned short* __restrict__ q_ws,   // bf16, pre-scaled by QSCALE
    const unsigned short* __restrict__ k_ws,
    const unsigned short* __restrict__ v_ws,
    const float* __restrict__ tm,
    unsigned short* __restrict__ att_ws,       // [32][512][384] bf16
    int qkv_stride, int toff0)
{
    int nc2 = blockIdx.x;
    int bp = blockIdx.y;
    int z  = blockIdx.z;
    int t = z >> 2, h = z & 3;
    size_t qoff = (size_t)t * (size_t)qkv_stride;
    const float* tmt = tm + (size_t)(t + (t >> 1)) * 262144;
    int toff = toff0 + t * 128;

    __shared__ unsigned short Vt[32][516];
    __shared__ unsigned short Ps[8][16][72];

    int tid = threadIdx.x, lane = tid & 63, wv = tid >> 6;
    int l15 = lane & 15, quad = lane >> 4;

    {
        const unsigned short* vp = v_ws + qoff + ((size_t)bp * 512 + tid) * 128 + h * 32;
        short8 a = *(const short8*)vp;
        short8 b = *(const short8*)(vp + 8);
        short8 c = *(const short8*)(vp + 16);
        short8 d = *(const short8*)(vp + 24);
        #pragma unroll
        for (int j = 0; j < 8; ++j) {
            Vt[j][tid]      = (unsigned short)a[j];
            Vt[8 + j][tid]  = (unsigned short)b[j];
            Vt[16 + j][tid] = (unsigned short)c[j];
            Vt[24 + j][tid] = (unsigned short)d[j];
        }
    }
    int n0 = nc2 * 256 + wv * 16;              // strip 0; strip 1 at n0+128
    short8 qf[2];
    qf[0] = *(const short8*)&q_ws[qoff +
        ((size_t)bp * 512 + n0 + l15) * 128 + h * 32 + quad * 8];
    qf[1] = *(const short8*)&q_ws[qoff +
        ((size_t)bp * 512 + n0 + 128 + l15) * 128 + h * 32 + quad * 8];
    __syncthreads();

    const unsigned short* Kb = k_ws + qoff + (size_t)bp * 512 * 128 + h * 32;
    // per-lane tm row base: n = n0 + l15 (+128 for strip 1), 4 consecutive m
    // starting at quad*4; all (c,ti) offsets fold into load immediates.
    const float* tp0 = tmt + (size_t)(n0 + l15) * 512 + quad * 4;

    floatx4 O0[2] = {{0.f,0.f,0.f,0.f},{0.f,0.f,0.f,0.f}};
    floatx4 O1[2] = {{0.f,0.f,0.f,0.f},{0.f,0.f,0.f,0.f}};
    float za[2] = {0.f, 0.f};
    const floatx4 zero4 = {0.f, 0.f, 0.f, 0.f};

    for (int c = 0; c < 8; ++c) {
        int mb = c * 64;
        short8 kf0 = *(const short8*)&Kb[(size_t)(mb +  0 + l15) * 128 + quad * 8];
        short8 kf1 = *(const short8*)&Kb[(size_t)(mb + 16 + l15) * 128 + quad * 8];
        short8 kf2 = *(const short8*)&Kb[(size_t)(mb + 32 + l15) * 128 + quad * 8];
        short8 kf3 = *(const short8*)&Kb[(size_t)(mb + 48 + l15) * 128 + quad * 8];

        #pragma unroll
        for (int s = 0; s < 2; ++s) {
            // S^T tiles: row m = mb+ti*16+quad*4+i, col n = ns+l15
            floatx4 S[4];
            S[0] = __builtin_amdgcn_mfma_f32_16x16x32_bf16(kf0, qf[s], zero4, 0, 0, 0);
            S[1] = __builtin_amdgcn_mfma_f32_16x16x32_bf16(kf1, qf[s], zero4, 0, 0, 0);
            S[2] = __builtin_amdgcn_mfma_f32_16x16x32_bf16(kf2, qf[s], zero4, 0, 0, 0);
            S[3] = __builtin_amdgcn_mfma_f32_16x16x32_bf16(kf3, qf[s], zero4, 0, 0, 0);

            const float* tps = tp0 + (size_t)s * 65536;   // +128 rows for strip 1
            #pragma unroll
            for (int ti = 0; ti < 4; ++ti) {
                floatx4 t4 = *(const floatx4*)(tps + mb + ti * 16);
                float w[4];
                #pragma unroll
                for (int i = 0; i < 4; ++i) {
                    float e = __builtin_amdgcn_exp2f(S[ti][i]);
                    // ceil(tm) is the 0/1 mask indicator (tm in {0} U (0,1])
                    za[s] = __builtin_fmaf(e, __builtin_ceilf(t4[i]), za[s]);
                    w[i] = e * t4[i];                     // ==0 when masked
                }
                uint2v pk;
                pk.x = cvt_pk_bf16(w[0], w[1]);
                pk.y = cvt_pk_bf16(w[2], w[3]);
                *(uint2v*)&Ps[wv][l15][ti * 16 + quad * 4] = pk;
            }
            #pragma unroll
            for (int kc = 0; kc < 2; ++kc) {
                short8 pa  = *(const short8*)&Ps[wv][l15][kc * 32 + quad * 8];
                short8 vb0 = *(const short8*)&Vt[l15][mb + kc * 32 + quad * 8];
                short8 vb1 = *(const short8*)&Vt[16 + l15][mb + kc * 32 + quad * 8];
                O0[s] = __builtin_amdgcn_mfma_f32_16x16x32_bf16(pa, vb0, O0[s], 0, 0, 0);
                O1[s] = __builtin_amdgcn_mfma_f32_16x16x32_bf16(pa, vb1, O1[s], 0, 0, 0);
            }
        }
    }

    #pragma unroll
    for (int s = 0; s < 2; ++s) {
        // za[s] holds the partial denominator for n = ns + l15 over this lane's
        // m residues (quad*4..quad*4+3 mod 16); reduce across quads.
        float zz = za[s];
        zz += __shfl_xor(zz, 16, 64);
        zz += __shfl_xor(zz, 32, 64);
        #pragma unroll
        for (int i = 0; i < 4; ++i) {
            // O rows are n = ns + quad*4 + i -> fetch za from lane quad*4+i
            float rz = 1.0f / __shfl(zz, quad * 4 + i, 64);
            size_t row = (size_t)bp * 512 + n0 + s * 128 + quad * 4 + i;
            att_ws[row * 384 + toff + h * 32 + l15]      = f2b(O0[s][i] * rz);
            att_ws[row * 384 + toff + h * 32 + 16 + l15] = f2b(O1[s][i] * rz);
        }
    }
}

// ---------------- K3a: out-projection from pre-converted Wo (proven) ----------
__global__ __launch_bounds__(256) void k_oproj_pre(
    const unsigned short* __restrict__ att_ws,   // [32][512][384] bf16
    const unsigned short* __restrict__ Wob,      // [128][384] bf16
    const float* __restrict__ X,
    const float* __restrict__ gamma,
    const float* __restrict__ beta,
    float* __restrict__ out)
{
    int bp = blockIdx.x;
    int mt = blockIdx.y;
    __shared__ unsigned short As[64 * 128];
    __shared__ unsigned short Ws[128 * 128];
    int tid = threadIdx.x, lane = tid & 63, wv = tid >> 6;
    int l15 = lane & 15, quad = lane >> 4;

    floatx4 acc[8];
    for (int ct = 0; ct < 8; ++ct) acc[ct] = (floatx4){0.f, 0.f, 0.f, 0.f};
    size_t rowbase = (size_t)bp * 512 + mt * 64;

    for (int kc = 0; kc < 3; ++kc) {
        __syncthreads();
        for (int i = 0; i < 4; ++i) {
            int flat = i * 256 + tid;
            int row = flat >> 4, colg = (flat & 15) * 8;
            *(short8*)&As[row * 128 + colg] =
                *(const short8*)&att_ws[(rowbase + row) * 384 + kc * 128 + colg];
        }
        for (int i = 0; i < 8; ++i) {
            int flat = i * 256 + tid;
            int row = flat >> 4, colg = (flat & 15) * 8;
            *(short8*)&Ws[row * 128 + colg] =
                *(const short8*)&Wob[(size_t)row * 384 + kc * 128 + colg];
        }
        __syncthreads();
        for (int ct = 0; ct < 8; ++ct) {
            for (int kk = 0; kk < 4; ++kk) {
                short8 a = *(const short8*)&As[(wv * 16 + l15) * 128 + kk * 32 + quad * 8];
                short8 b = *(const short8*)&Ws[(ct * 16 + l15) * 128 + kk * 32 + quad * 8];
                acc[ct] = __builtin_amdgcn_mfma_f32_16x16x32_bf16(a, b, acc[ct], 0, 0, 0);
            }
        }
    }

    for (int i = 0; i < 4; ++i) {
        int lrow = wv * 16 + quad * 4 + i;
        size_t grow = rowbase + lrow;
        float vals[8];
        float s = 0.f, sq = 0.f;
        for (int ct = 0; ct < 8; ++ct) {
            int col = ct * 16 + l15;
            float v = acc[ct][i] + X[grow * 128 + col];
            vals[ct] = v;
            s += v; sq += v * v;
        }
        for (int d = 1; d < 16; d <<= 1) {
            s  += __shfl_xor(s, d, 64);
            sq += __shfl_xor(sq, d, 64);
        }
        float mu = s * (1.0f / 128.0f);
        float var = sq * (1.0f / 128.0f) - mu * mu;
        float rs = rsqrtf(var + 1e-5f);
        for (int ct = 0; ct < 8; ++ct) {
            int col = ct * 16 + l15;
            out[grow * 128 + col] = (vals[ct] - mu) * rs * gamma[col] + beta[col];
        }
    }
}

// ---------------- K3b: out-projection, inline-cvt fallback --------------------
__global__ __launch_bounds__(256) void k_oproj_cvt(
    const unsigned short* __restrict__ att_ws,
    const float* __restrict__ Wo,
    const float* __restrict__ X,
    const float* __restrict__ gamma,
    const float* __restrict__ beta,
    float* __restrict__ out)
{
    int bp = blockIdx.x;
    int mt = blockIdx.y;
    __shared__ unsigned short As[64 * 128];
    __shared__ unsigned short Ws[128 * 128];
    int tid = threadIdx.x, lane = tid & 63, wv = tid >> 6;
    int l15 = lane & 15, quad = lane >> 4;

    floatx4 acc[8];
    for (int ct = 0; ct < 8; ++ct) acc[ct] = (floatx4){0.f, 0.f, 0.f, 0.f};
    size_t rowbase = (size_t)bp * 512 + mt * 64;

    for (int kc = 0; kc < 3; ++kc) {
        __syncthreads();
        for (int i = 0; i < 4; ++i) {
            int flat = i * 256 + tid;
            int row = flat >> 4, colg = (flat & 15) * 8;
            *(short8*)&As[row * 128 + colg] =
                *(const short8*)&att_ws[(rowbase + row) * 384 + kc * 128 + colg];
        }
        for (int i = 0; i < 8; ++i) {
            int flat = i * 256 + tid;
            int row = flat >> 4, colg = (flat & 15) * 8;
            *(short8*)&Ws[row * 128 + colg] = cvt8(&Wo[(size_t)row * 384 + kc * 128 + colg]);
        }
        __syncthreads();
        for (int ct = 0; ct < 8; ++ct) {
            for (int kk = 0; kk < 4; ++kk) {
                short8 a = *(const short8*)&As[(wv * 16 + l15) * 128 + kk * 32 + quad * 8];
                short8 b = *(const short8*)&Ws[(ct * 16 + l15) * 128 + kk * 32 + quad * 8];
                acc[ct] = __builtin_amdgcn_mfma_f32_16x16x32_bf16(a, b, acc[ct], 0, 0, 0);
            }
        }
    }

    for (int i = 0; i < 4; ++i) {
        int lrow = wv * 16 + quad * 4 + i;
        size_t grow = rowbase + lrow;
        float vals[8];
        float s = 0.f, sq = 0.f;
        for (int ct = 0; ct < 8; ++ct) {
            int col = ct * 16 + l15;
            float v = acc[ct][i] + X[grow * 128 + col];
            vals[ct] = v;
            s += v; sq += v * v;
        }
        for (int d = 1; d < 16; d <<= 1) {
            s  += __shfl_xor(s, d, 64);
            sq += __shfl_xor(sq, d, 64);
        }
        float mu = s * (1.0f / 128.0f);
        float var = sq * (1.0f / 128.0f) - mu * mu;
        float rs = rsqrtf(var + 1e-5f);
        for (int ct = 0; ct < 8; ++ct) {
            int col = ct * 16 + l15;
            out[grow * 128 + col] = (vals[ct] - mu) * rs * gamma[col] + beta[col];
        }
    }
}

// ---------------- launcher ----------------
extern "C" void kernel_launch(void* const* d_in, const int* in_sizes, int n_in,
                              void* d_out, int out_size, void* d_ws, size_t ws_size,
                              hipStream_t stream) {
    const float* X     = (const float*)d_in[0];
    const float* TM    = (const float*)d_in[2];
    const float* Wq    = (const float*)d_in[3];
    const float* Wk    = (const float*)d_in[4];
    const float* Wv    = (const float*)d_in[5];
    const float* Wo    = (const float*)d_in[6];
    const float* gamma = (const float*)d_in[7];
    const float* beta  = (const float*)d_in[8];
    float* out = (float*)d_out;

    char* ws = (char*)d_ws;
    const size_t QKV1 = 2097152;             // elems per t per tensor
    const size_t QKV1B = QKV1 * 2;           // 4 MB

    if (ws_size >= WS_XL) {
        unsigned short* q3  = (unsigned short*)(ws);
        unsigned short* k3  = (unsigned short*)(ws + 3 * QKV1B);
        unsigned short* v3  = (unsigned short*)(ws + 6 * QKV1B);
        unsigned short* att = (unsigned short*)(ws + 9 * QKV1B);
        unsigned short* Xb  = (unsigned short*)(ws + 50331648ull);
        unsigned short* Wb  = (unsigned short*)(ws + 54525952ull);
        unsigned short* Wob = (unsigned short*)(ws + 54820864ull);
        k_prep<<<dim3(1120), 256, 0, stream>>>(X, Wq, Wk, Wv, Wo, Xb, Wb, Wob);
        k_qkv_pre<<<dim3(32, 4, 3), 256, 0, stream>>>(Xb, Wb, q3, k3, v3);
        k_attn3<<<dim3(2, 32, 12), 512, 0, stream>>>(q3, k3, v3, TM, att, (int)QKV1, 0);
        k_oproj_pre<<<dim3(32, 8), 256, 0, stream>>>(att, Wob, X, gamma, beta, out);
    } else if (ws_size >= WS_BIG) {
        unsigned short* q3  = (unsigned short*)(ws);
        unsigned short* k3  = (unsigned short*)(ws + 3 * QKV1B);
        unsigned short* v3  = (unsigned short*)(ws + 6 * QKV1B);
        unsigned short* att = (unsigned short*)(ws + 9 * QKV1B);
        k_qkv_cvt<<<dim3(32, 4, 3), 256, 0, stream>>>(
            X, Wq, Wk, Wv, q3, k3, v3, 16384, (int)QKV1);
        k_attn3<<<dim3(2, 32, 12), 512, 0, stream>>>(q3, k3, v3, TM, att, (int)QKV1, 0);
        k_oproj_cvt<<<dim3(32, 8), 256, 0, stream>>>(att, Wo, X, gamma, beta, out);
    } else {
        unsigned short* q_ws   = (unsigned short*)(ws);
        unsigned short* k_ws   = (unsigned short*)(ws + QKV1B);
        unsigned short* v_ws   = (unsigned short*)(ws + 2 * QKV1B);
        unsigned short* att_ws = (unsigned short*)(ws + 3 * QKV1B);
        const int tsel[3] = {0, 1, 3};
        for (int t = 0; t < 3; ++t) {
            k_qkv_cvt<<<dim3(32, 4, 1), 256, 0, stream>>>(
                X, Wq + (size_t)t * 16384, Wk + (size_t)t * 16384, Wv + (size_t)t * 16384,
                q_ws, k_ws, v_ws, 0, 0);
            k_attn3<<<dim3(2, 32, 4), 512, 0, stream>>>(
                q_ws, k_ws, v_ws, TM + (size_t)tsel[t] * 262144, att_ws, 0, t * 128);
        }
        k_oproj_cvt<<<dim3(32, 8), 256, 0, stream>>>(att_ws, Wo, X, gamma, beta, out);
    }
}

// Round 2
// 170.367 us; speedup vs baseline: 1.1516x; 1.1516x over previous
//
#include <hip/hip_runtime.h>

// ---------------- problem constants ----------------
// B*P=32, N=512, D=128, H=4, DK=32, T=3 (tm {0,1,3}; tsel(t)=t+(t>>1))
// Inputs f32, OUTPUT f32. XL path (ws >= 54.9MB) confirmed.
// R13: 171.5us total; k_attn2 57us (MfmaUtil 8.6 / VALUBusy 36 / HBM 11%).
// R14 FAILED (196us, k_attn 81.7us): transposed-S P-loop cut VALU work but
//   added a 16-deep serial za fma chain + 4-way bank conflict on b64 P stores
//   (SQ_LDS_BANK_CONFLICT 786K->2.36M). k_attn is latency- not issue-bound.
// R15: revert k_attn to proven k_attn2; attack the OTHER 114us instead:
//   k_qkv: qkv loop -> grid z (32,4,9)=1152 blocks (was 384 = 1.5/CU).
//   k_oproj: (32,8)x4waves/1blk/CU -> (32,16) 32-row blocks, waves split
//   ct-halves, LN partials merged via LDS; 40.5KB LDS -> 3 blocks/CU capacity.

typedef __attribute__((ext_vector_type(8))) short  short8;
typedef __attribute__((ext_vector_type(4))) float  floatx4;

#define WS_BIG   50331648ull                  // q3/k3/v3 (37.7MB) + att (12.6MB)
#define WS_XL    54919168ull                  // + Xb 4MB + Wb 288KB + Wob 96KB
#define QSCALE   0.25503486f                  // (1/sqrt(32)) * log2(e)

__device__ __forceinline__ float b2f(unsigned short u) {
    union { unsigned int i; float f; } v; v.i = ((unsigned int)u) << 16; return v.f;
}
__device__ __forceinline__ unsigned short f2b(float f) {
    union { float f; unsigned int i; } v; v.f = f;
    unsigned int x = v.i;
    return (unsigned short)((x + 0x7fffu + ((x >> 16) & 1u)) >> 16);
}
__device__ __forceinline__ unsigned int fbits(float f) {
    union { float f; unsigned int i; } v; v.f = f; return v.i;
}
__device__ __forceinline__ short8 cvt8(const float* p) {
    floatx4 a = *(const floatx4*)p;
    floatx4 b = *(const floatx4*)(p + 4);
    short8 r;
    r[0] = (short)f2b(a[0]); r[1] = (short)f2b(a[1]);
    r[2] = (short)f2b(a[2]); r[3] = (short)f2b(a[3]);
    r[4] = (short)f2b(b[0]); r[5] = (short)f2b(b[1]);
    r[6] = (short)f2b(b[2]); r[7] = (short)f2b(b[3]);
    return r;
}

// ---------------- K0: one-time f32->bf16 conversion of X, Wq/Wk/Wv, Wo --------
__global__ __launch_bounds__(256) void k_prep(
    const float* __restrict__ X,  const float* __restrict__ Wq,
    const float* __restrict__ Wk, const float* __restrict__ Wv,
    const float* __restrict__ Wo,
    unsigned short* __restrict__ Xb, unsigned short* __restrict__ Wb,
    unsigned short* __restrict__ Wob)
{
    size_t i = ((size_t)blockIdx.x * 256 + threadIdx.x) * 8;
    const float* src; unsigned short* dst; size_t off;
    if      (i < 2097152) { src = X;  dst = Xb;          off = i; }
    else if (i < 2146304) { src = Wq; dst = Wb;          off = i - 2097152; }
    else if (i < 2195456) { src = Wk; dst = Wb + 49152;  off = i - 2146304; }
    else if (i < 2244608) { src = Wv; dst = Wb + 98304;  off = i - 2195456; }
    else                  { src = Wo; dst = Wob;         off = i - 2244608; }
    *(short8*)&dst[off] = cvt8(&src[off]);
}

// ---------------- K1a: QKV projection, one (qkv,t) per block (R15) ------------
// grid (32 bp, 4 mt, 9 z) = 1152 blocks (~4.5/CU, 2 resident @64KB LDS) vs the
// old 384 (1.5/CU). Per-block serial ct chain drops 3x; X tile re-staged from
// L2 (Xb 4MB, L2-resident).
__global__ __launch_bounds__(256) void k_qkv_pre2(
    const unsigned short* __restrict__ Xb,   // [32][512][128] bf16
    const unsigned short* __restrict__ Wb,   // [3 qkv][3 t][128][128] bf16
    unsigned short* __restrict__ q_ws,
    unsigned short* __restrict__ k_ws,
    unsigned short* __restrict__ v_ws)
{
    int bp = blockIdx.x, mt = blockIdx.y, z = blockIdx.z;
    int qkv = z / 3, t = z % 3;
    __shared__ unsigned short Xs[128 * 128];     // 32 KB
    __shared__ unsigned short Cs[4][32 * 128];   // 32 KB (8KB per wave)
    int tid = threadIdx.x;
    int lane = tid & 63, wv = tid >> 6;
    int l15 = lane & 15, quad = lane >> 4;

    const unsigned short* Xbase = Xb + ((size_t)bp * 512 + mt * 128) * 128;
    for (int i = 0; i < 8; ++i) {
        int e = (i * 256 + tid) * 8;
        *(short8*)&Xs[e] = *(const short8*)&Xbase[e];
    }
    __syncthreads();

    unsigned short* Osel[3] = { q_ws, k_ws, v_ws };
    int rt0 = wv * 2, rt1 = wv * 2 + 1;

    const unsigned short* Wt = Wb + qkv * 49152 + t * 16384;
    unsigned short* Ob = Osel[qkv] + (size_t)t * 2097152
                       + ((size_t)bp * 512 + mt * 128 + wv * 32) * 128;
    float sc = (qkv == 0) ? QSCALE : 1.0f;

    for (int ct = 0; ct < 8; ++ct) {
        short8 bfr[4];
        for (int kk = 0; kk < 4; ++kk)
            bfr[kk] = *(const short8*)&Wt[(size_t)(ct * 16 + l15) * 128 + kk * 32 + quad * 8];
        floatx4 acc0 = {0.f, 0.f, 0.f, 0.f};
        floatx4 acc1 = {0.f, 0.f, 0.f, 0.f};
        for (int kk = 0; kk < 4; ++kk) {
            short8 a0 = *(const short8*)&Xs[(rt0 * 16 + l15) * 128 + kk * 32 + quad * 8];
            short8 a1 = *(const short8*)&Xs[(rt1 * 16 + l15) * 128 + kk * 32 + quad * 8];
            acc0 = __builtin_amdgcn_mfma_f32_16x16x32_bf16(a0, bfr[kk], acc0, 0, 0, 0);
            acc1 = __builtin_amdgcn_mfma_f32_16x16x32_bf16(a1, bfr[kk], acc1, 0, 0, 0);
        }
        #pragma unroll
        for (int i = 0; i < 4; ++i) {
            int row = quad * 4 + i;
            int swz = (row & 7) << 4;
            int col = (ct * 16 + l15) ^ swz;
            Cs[wv][row * 128 + col]        = f2b(acc0[i] * sc);
            Cs[wv][(16 + row) * 128 + col] = f2b(acc1[i] * sc);
        }
    }
    #pragma unroll
    for (int j = 0; j < 8; ++j) {
        int flat = j * 64 + lane;
        int r = flat >> 4;
        int cg = (flat & 15) * 8;
        int cgs = cg ^ ((r & 7) << 4);
        *(short8*)&Ob[(size_t)r * 128 + cg] = *(const short8*)&Cs[wv][r * 128 + cgs];
    }
}

// ---------------- K1b: QKV projection, inline-cvt fallback (unchanged) --------
__global__ __launch_bounds__(256) void k_qkv_cvt(
    const float* __restrict__ X,
    const float* __restrict__ Wq, const float* __restrict__ Wk,
    const float* __restrict__ Wv,
    unsigned short* __restrict__ q_ws, unsigned short* __restrict__ k_ws,
    unsigned short* __restrict__ v_ws,
    int wstride, int ostride)
{
    int bp = blockIdx.x, mt = blockIdx.y, tz = blockIdx.z;
    __shared__ unsigned short Xs[128 * 128];
    int tid = threadIdx.x;
    int lane = tid & 63, wv = tid >> 6;
    int l15 = lane & 15, quad = lane >> 4;

    const float* Xbase = X + ((size_t)bp * 512 + mt * 128) * 128;
    for (int i = 0; i < 8; ++i) {
        int e = (i * 256 + tid) * 8;
        *(short8*)&Xs[e] = cvt8(&Xbase[e]);
    }
    __syncthreads();

    size_t woff = (size_t)tz * wstride;
    size_t ooff = (size_t)tz * ostride;
    const float* Wsel[3] = { Wq + woff, Wk + woff, Wv + woff };
    unsigned short* Osel[3] = { q_ws + ooff, k_ws + ooff, v_ws + ooff };

    for (int qkv = 0; qkv < 3; ++qkv) {
        const float* Wt = Wsel[qkv];
        unsigned short* Ob = Osel[qkv] + ((size_t)bp * 512 + mt * 128) * 128;
        float sc = (qkv == 0) ? QSCALE : 1.0f;
        for (int ct = 0; ct < 8; ++ct) {
            short8 bfr[4];
            for (int kk = 0; kk < 4; ++kk)
                bfr[kk] = cvt8(&Wt[(size_t)(ct * 16 + l15) * 128 + kk * 32 + quad * 8]);
            floatx4 acc0 = {0.f, 0.f, 0.f, 0.f};
            floatx4 acc1 = {0.f, 0.f, 0.f, 0.f};
            int rt0 = wv * 2, rt1 = wv * 2 + 1;
            for (int kk = 0; kk < 4; ++kk) {
                short8 a0 = *(const short8*)&Xs[(rt0 * 16 + l15) * 128 + kk * 32 + quad * 8];
                short8 a1 = *(const short8*)&Xs[(rt1 * 16 + l15) * 128 + kk * 32 + quad * 8];
                acc0 = __builtin_amdgcn_mfma_f32_16x16x32_bf16(a0, bfr[kk], acc0, 0, 0, 0);
                acc1 = __builtin_amdgcn_mfma_f32_16x16x32_bf16(a1, bfr[kk], acc1, 0, 0, 0);
            }
            int col = ct * 16 + l15;
            for (int i = 0; i < 4; ++i) {
                Ob[(size_t)(rt0 * 16 + quad * 4 + i) * 128 + col] = f2b(acc0[i] * sc);
                Ob[(size_t)(rt1 * 16 + quad * 4 + i) * 128 + col] = f2b(acc1[i] * sc);
            }
        }
    }
}

// ---------------- K2: dense MFMA attention (R13-proven, reverted) -------------
// grid (nc2=2, bp=32, z=t*4+h) = 768 blocks = exactly 3/CU (52KB LDS allows 3).
// Wave wv handles strips n0 = nc2*256 + wv*16 and n0+128 against each staged
// K chunk: K fetch /2, V staging /2, 2 independent exp chains for ILP.
__global__ __launch_bounds__(512) void k_attn2(
    const unsigned short* __restrict__ q_ws,   // bf16, pre-scaled by QSCALE
    const unsigned short* __restrict__ k_ws,
    const unsigned short* __restrict__ v_ws,
    const float* __restrict__ tm,
    unsigned short* __restrict__ att_ws,       // [32][512][384] bf16
    int qkv_stride, int toff0)
{
    int nc2 = blockIdx.x;
    int bp = blockIdx.y;
    int z  = blockIdx.z;
    int t = z >> 2, h = z & 3;
    size_t qoff = (size_t)t * (size_t)qkv_stride;
    const float* tmt = tm + (size_t)(t + (t >> 1)) * 262144;
    int toff = toff0 + t * 128;

    __shared__ unsigned short Vt[32][516];
    __shared__ unsigned short Ps[8][16][72];

    int tid = threadIdx.x, lane = tid & 63, wv = tid >> 6;
    int l15 = lane & 15, quad = lane >> 4;

    {
        const unsigned short* vp = v_ws + qoff + ((size_t)bp * 512 + tid) * 128 + h * 32;
        short8 a = *(const short8*)vp;
        short8 b = *(const short8*)(vp + 8);
        short8 c = *(const short8*)(vp + 16);
        short8 d = *(const short8*)(vp + 24);
        #pragma unroll
        for (int j = 0; j < 8; ++j) {
            Vt[j][tid]      = (unsigned short)a[j];
            Vt[8 + j][tid]  = (unsigned short)b[j];
            Vt[16 + j][tid] = (unsigned short)c[j];
            Vt[24 + j][tid] = (unsigned short)d[j];
        }
    }
    int n0 = nc2 * 256 + wv * 16;              // strip 0; strip 1 at n0+128
    short8 qf[2];
    qf[0] = *(const short8*)&q_ws[qoff +
        ((size_t)bp * 512 + n0 + l15) * 128 + h * 32 + quad * 8];
    qf[1] = *(const short8*)&q_ws[qoff +
        ((size_t)bp * 512 + n0 + 128 + l15) * 128 + h * 32 + quad * 8];
    __syncthreads();

    const unsigned short* Kb = k_ws + qoff + (size_t)bp * 512 * 128 + h * 32;
    floatx4 O0[2] = {{0.f,0.f,0.f,0.f},{0.f,0.f,0.f,0.f}};
    floatx4 O1[2] = {{0.f,0.f,0.f,0.f},{0.f,0.f,0.f,0.f}};
    float za[2][4] = {{0.f,0.f,0.f,0.f},{0.f,0.f,0.f,0.f}};
    const floatx4 zero4 = {0.f, 0.f, 0.f, 0.f};

    for (int c = 0; c < 8; ++c) {
        int mb = c * 64;
        short8 kf0 = *(const short8*)&Kb[(size_t)(mb +  0 + l15) * 128 + quad * 8];
        short8 kf1 = *(const short8*)&Kb[(size_t)(mb + 16 + l15) * 128 + quad * 8];
        short8 kf2 = *(const short8*)&Kb[(size_t)(mb + 32 + l15) * 128 + quad * 8];
        short8 kf3 = *(const short8*)&Kb[(size_t)(mb + 48 + l15) * 128 + quad * 8];

        #pragma unroll
        for (int s = 0; s < 2; ++s) {
            int ns = n0 + s * 128;
            floatx4 S[4];
            S[0] = __builtin_amdgcn_mfma_f32_16x16x32_bf16(qf[s], kf0, zero4, 0, 0, 0);
            S[1] = __builtin_amdgcn_mfma_f32_16x16x32_bf16(qf[s], kf1, zero4, 0, 0, 0);
            S[2] = __builtin_amdgcn_mfma_f32_16x16x32_bf16(qf[s], kf2, zero4, 0, 0, 0);
            S[3] = __builtin_amdgcn_mfma_f32_16x16x32_bf16(qf[s], kf3, zero4, 0, 0, 0);

            #pragma unroll
            for (int ti = 0; ti < 4; ++ti) {
                int m = mb + ti * 16 + l15;
                #pragma unroll
                for (int i = 0; i < 4; ++i) {
                    float tmv = tmt[(size_t)(ns + quad * 4 + i) * 512 + m];
                    float e = __builtin_amdgcn_exp2f(S[ti][i]);
                    za[s][i] += (tmv != 0.0f) ? e : 0.0f;
                    float w = e * tmv;                    // ==0 when masked
                    Ps[wv][quad * 4 + i][ti * 16 + l15] =
                        (unsigned short)((fbits(w) + 0x8000u) >> 16);  // half-up
                }
            }
            #pragma unroll
            for (int kc = 0; kc < 2; ++kc) {
                short8 pa  = *(const short8*)&Ps[wv][l15][kc * 32 + quad * 8];
                short8 vb0 = *(const short8*)&Vt[l15][mb + kc * 32 + quad * 8];
                short8 vb1 = *(const short8*)&Vt[16 + l15][mb + kc * 32 + quad * 8];
                O0[s] = __builtin_amdgcn_mfma_f32_16x16x32_bf16(pa, vb0, O0[s], 0, 0, 0);
                O1[s] = __builtin_amdgcn_mfma_f32_16x16x32_bf16(pa, vb1, O1[s], 0, 0, 0);
            }
        }
    }

    #pragma unroll
    for (int s = 0; s < 2; ++s) {
        #pragma unroll
        for (int d = 1; d < 16; d <<= 1) {
            #pragma unroll
            for (int i = 0; i < 4; ++i) za[s][i] += __shfl_xor(za[s][i], d, 64);
        }
        #pragma unroll
        for (int i = 0; i < 4; ++i) {
            float rz = 1.0f / za[s][i];
            size_t row = (size_t)bp * 512 + n0 + s * 128 + quad * 4 + i;
            att_ws[row * 384 + toff + h * 32 + l15]      = f2b(O0[s][i] * rz);
            att_ws[row * 384 + toff + h * 32 + 16 + l15] = f2b(O1[s][i] * rz);
        }
    }
}

// ---------------- K3a: out-projection, 32-row blocks + ct-split waves (R15) ---
// grid (32, 16) = 512 blocks, 256 thr. Wave wv: row-tile (wv&1), ct-half
// (wv>>1). LDS 8KB As + 32KB Ws + 512B LN partials = 40.5KB -> 3 blocks/CU
// capacity, 2 resident. LN row stats merged across the ct-half wave pair.
__global__ __launch_bounds__(256) void k_oproj_pre2(
    const unsigned short* __restrict__ att_ws,   // [32][512][384] bf16
    const unsigned short* __restrict__ Wob,      // [128][384] bf16
    const float* __restrict__ X,
    const float* __restrict__ gamma,
    const float* __restrict__ beta,
    float* __restrict__ out)
{
    int bp = blockIdx.x;
    int mt = blockIdx.y;                         // 16 tiles of 32 rows
    __shared__ unsigned short As[32 * 128];      // 8 KB
    __shared__ unsigned short Ws[128 * 128];     // 32 KB
    __shared__ float Ls_s[2][32];                // per-ct-half row partials
    __shared__ float Ls_q[2][32];
    int tid = threadIdx.x, lane = tid & 63, wv = tid >> 6;
    int l15 = lane & 15, quad = lane >> 4;
    int rtile = wv & 1, chalf = wv >> 1;

    floatx4 acc[4];
    for (int ct = 0; ct < 4; ++ct) acc[ct] = (floatx4){0.f, 0.f, 0.f, 0.f};
    size_t rowbase = (size_t)bp * 512 + mt * 32;

    for (int kc = 0; kc < 3; ++kc) {
        __syncthreads();
        for (int i = 0; i < 2; ++i) {
            int flat = i * 256 + tid;
            int row = flat >> 4, colg = (flat & 15) * 8;
            *(short8*)&As[row * 128 + colg] =
                *(const short8*)&att_ws[(rowbase + row) * 384 + kc * 128 + colg];
        }
        for (int i = 0; i < 8; ++i) {
            int flat = i * 256 + tid;
            int row = flat >> 4, colg = (flat & 15) * 8;
            *(short8*)&Ws[row * 128 + colg] =
                *(const short8*)&Wob[(size_t)row * 384 + kc * 128 + colg];
        }
        __syncthreads();
        for (int ct = 0; ct < 4; ++ct) {
            for (int kk = 0; kk < 4; ++kk) {
                short8 a = *(const short8*)&As[(rtile * 16 + l15) * 128 + kk * 32 + quad * 8];
                short8 b = *(const short8*)&Ws[((chalf * 4 + ct) * 16 + l15) * 128 + kk * 32 + quad * 8];
                acc[ct] = __builtin_amdgcn_mfma_f32_16x16x32_bf16(a, b, acc[ct], 0, 0, 0);
            }
        }
    }

    float vals[4][4];                            // [i][ct], static indexing
    #pragma unroll
    for (int i = 0; i < 4; ++i) {
        int lrow = rtile * 16 + quad * 4 + i;
        size_t grow = rowbase + lrow;
        float s = 0.f, sq = 0.f;
        #pragma unroll
        for (int ct = 0; ct < 4; ++ct) {
            int col = (chalf * 4 + ct) * 16 + l15;
            float v = acc[ct][i] + X[grow * 128 + col];
            vals[i][ct] = v;
            s += v; sq += v * v;
        }
        #pragma unroll
        for (int d = 1; d < 16; d <<= 1) {
            s  += __shfl_xor(s, d, 64);
            sq += __shfl_xor(sq, d, 64);
        }
        if (l15 == 0) { Ls_s[chalf][lrow] = s; Ls_q[chalf][lrow] = sq; }
    }
    __syncthreads();
    #pragma unroll
    for (int i = 0; i < 4; ++i) {
        int lrow = rtile * 16 + quad * 4 + i;
        size_t grow = rowbase + lrow;
        float st  = Ls_s[0][lrow] + Ls_s[1][lrow];
        float sqt = Ls_q[0][lrow] + Ls_q[1][lrow];
        float mu = st * (1.0f / 128.0f);
        float var = sqt * (1.0f / 128.0f) - mu * mu;
        float rs = rsqrtf(var + 1e-5f);
        #pragma unroll
        for (int ct = 0; ct < 4; ++ct) {
            int col = (chalf * 4 + ct) * 16 + l15;
            out[grow * 128 + col] = (vals[i][ct] - mu) * rs * gamma[col] + beta[col];
        }
    }
}

// ---------------- K3b: out-projection, inline-cvt fallback (unchanged) --------
__global__ __launch_bounds__(256) void k_oproj_cvt(
    const unsigned short* __restrict__ att_ws,
    const float* __restrict__ Wo,
    const float* __restrict__ X,
    const float* __restrict__ gamma,
    const float* __restrict__ beta,
    float* __restrict__ out)
{
    int bp = blockIdx.x;
    int mt = blockIdx.y;
    __shared__ unsigned short As[64 * 128];
    __shared__ unsigned short Ws[128 * 128];
    int tid = threadIdx.x, lane = tid & 63, wv = tid >> 6;
    int l15 = lane & 15, quad = lane >> 4;

    floatx4 acc[8];
    for (int ct = 0; ct < 8; ++ct) acc[ct] = (floatx4){0.f, 0.f, 0.f, 0.f};
    size_t rowbase = (size_t)bp * 512 + mt * 64;

    for (int kc = 0; kc < 3; ++kc) {
        __syncthreads();
        for (int i = 0; i < 4; ++i) {
            int flat = i * 256 + tid;
            int row = flat >> 4, colg = (flat & 15) * 8;
            *(short8*)&As[row * 128 + colg] =
                *(const short8*)&att_ws[(rowbase + row) * 384 + kc * 128 + colg];
        }
        for (int i = 0; i < 8; ++i) {
            int flat = i * 256 + tid;
            int row = flat >> 4, colg = (flat & 15) * 8;
            *(short8*)&Ws[row * 128 + colg] = cvt8(&Wo[(size_t)row * 384 + kc * 128 + colg]);
        }
        __syncthreads();
        for (int ct = 0; ct < 8; ++ct) {
            for (int kk = 0; kk < 4; ++kk) {
                short8 a = *(const short8*)&As[(wv * 16 + l15) * 128 + kk * 32 + quad * 8];
                short8 b = *(const short8*)&Ws[(ct * 16 + l15) * 128 + kk * 32 + quad * 8];
                acc[ct] = __builtin_amdgcn_mfma_f32_16x16x32_bf16(a, b, acc[ct], 0, 0, 0);
            }
        }
    }

    for (int i = 0; i < 4; ++i) {
        int lrow = wv * 16 + quad * 4 + i;
        size_t grow = rowbase + lrow;
        float vals[8];
        float s = 0.f, sq = 0.f;
        for (int ct = 0; ct < 8; ++ct) {
            int col = ct * 16 + l15;
            float v = acc[ct][i] + X[grow * 128 + col];
            vals[ct] = v;
            s += v; sq += v * v;
        }
        for (int d = 1; d < 16; d <<= 1) {
            s  += __shfl_xor(s, d, 64);
            sq += __shfl_xor(sq, d, 64);
        }
        float mu = s * (1.0f / 128.0f);
        float var = sq * (1.0f / 128.0f) - mu * mu;
        float rs = rsqrtf(var + 1e-5f);
        for (int ct = 0; ct < 8; ++ct) {
            int col = ct * 16 + l15;
            out[grow * 128 + col] = (vals[ct] - mu) * rs * gamma[col] + beta[col];
        }
    }
}

// ---------------- launcher ----------------
extern "C" void kernel_launch(void* const* d_in, const int* in_sizes, int n_in,
                              void* d_out, int out_size, void* d_ws, size_t ws_size,
                              hipStream_t stream) {
    const float* X     = (const float*)d_in[0];
    const float* TM    = (const float*)d_in[2];
    const float* Wq    = (const float*)d_in[3];
    const float* Wk    = (const float*)d_in[4];
    const float* Wv    = (const float*)d_in[5];
    const float* Wo    = (const float*)d_in[6];
    const float* gamma = (const float*)d_in[7];
    const float* beta  = (const float*)d_in[8];
    float* out = (float*)d_out;

    char* ws = (char*)d_ws;
    const size_t QKV1 = 2097152;             // elems per t per tensor
    const size_t QKV1B = QKV1 * 2;           // 4 MB

    if (ws_size >= WS_XL) {
        unsigned short* q3  = (unsigned short*)(ws);
        unsigned short* k3  = (unsigned short*)(ws + 3 * QKV1B);
        unsigned short* v3  = (unsigned short*)(ws + 6 * QKV1B);
        unsigned short* att = (unsigned short*)(ws + 9 * QKV1B);
        unsigned short* Xb  = (unsigned short*)(ws + 50331648ull);
        unsigned short* Wb  = (unsigned short*)(ws + 54525952ull);
        unsigned short* Wob = (unsigned short*)(ws + 54820864ull);
        k_prep<<<dim3(1120), 256, 0, stream>>>(X, Wq, Wk, Wv, Wo, Xb, Wb, Wob);
        k_qkv_pre2<<<dim3(32, 4, 9), 256, 0, stream>>>(Xb, Wb, q3, k3, v3);
        k_attn2<<<dim3(2, 32, 12), 512, 0, stream>>>(q3, k3, v3, TM, att, (int)QKV1, 0);
        k_oproj_pre2<<<dim3(32, 16), 256, 0, stream>>>(att, Wob, X, gamma, beta, out);
    } else if (ws_size >= WS_BIG) {
        unsigned short* q3  = (unsigned short*)(ws);
        unsigned short* k3  = (unsigned short*)(ws + 3 * QKV1B);
        unsigned short* v3  = (unsigned short*)(ws + 6 * QKV1B);
        unsigned short* att = (unsigned short*)(ws + 9 * QKV1B);
        k_qkv_cvt<<<dim3(32, 4, 3), 256, 0, stream>>>(
            X, Wq, Wk, Wv, q3, k3, v3, 16384, (int)QKV1);
        k_attn2<<<dim3(2, 32, 12), 512, 0, stream>>>(q3, k3, v3, TM, att, (int)QKV1, 0);
        k_oproj_cvt<<<dim3(32, 8), 256, 0, stream>>>(att, Wo, X, gamma, beta, out);
    } else {
        unsigned short* q_ws   = (unsigned short*)(ws);
        unsigned short* k_ws   = (unsigned short*)(ws + QKV1B);
        unsigned short* v_ws   = (unsigned short*)(ws + 2 * QKV1B);
        unsigned short* att_ws = (unsigned short*)(ws + 3 * QKV1B);
        const int tsel[3] = {0, 1, 3};
        for (int t = 0; t < 3; ++t) {
            k_qkv_cvt<<<dim3(32, 4, 1), 256, 0, stream>>>(
                X, Wq + (size_t)t * 16384, Wk + (size_t)t * 16384, Wv + (size_t)t * 16384,
                q_ws, k_ws, v_ws, 0, 0);
            k_attn2<<<dim3(2, 32, 4), 512, 0, stream>>>(
                q_ws, k_ws, v_ws, TM + (size_t)tsel[t] * 262144, att_ws, 0, t * 128);
        }
        k_oproj_cvt<<<dim3(32, 8), 256, 0, stream>>>(att_ws, Wo, X, gamma, beta, out);
    }
}

// Round 3
// 165.397 us; speedup vs baseline: 1.1862x; 1.0301x over previous
//
#include <hip/hip_runtime.h>

// ---------------- problem constants ----------------
// B*P=32, N=512, D=128, H=4, DK=32, T=3 (tm {0,1,3}; tsel(t)=t+(t>>1))
// Inputs f32, OUTPUT f32. XL path (ws >= 54.9MB) confirmed.
// R13: 171.5us total; k_attn2 57us (MfmaUtil 8.6 / VALUBusy 36 / HBM 11%).
// R14 FAILED: transposed-S P-loop -> serial za chain + 4-way LDS conflict.
// R15: 170.4us. k_attn2 reverted (back to 56-58us, proven). k_qkv/k_oproj
//   restructures moved total by only -1.1us -> non-attn budget is launch/
//   harness overhead + already-small kernels. Only k_attn moves dur_us.
// R16: k_attn4 = k_attn2 + depth-1 software pipeline on tm loads:
//   two 16-float register sets (tmA/tmB) rotate; body (c,s) issues the loads
//   for the NEXT (c,s) before its MFMAs, consumes the set issued one body
//   ago (~350cy earlier) -> L2 latency (~200cy) off the critical path.
//   Rolling base pointer tpc (+64/c) keeps address VALU ~2 ops/c.
//   P-store layout / za[2][4] / V staging / epilogue identical to R13.

typedef __attribute__((ext_vector_type(8))) short  short8;
typedef __attribute__((ext_vector_type(4))) float  floatx4;

#define WS_BIG   50331648ull                  // q3/k3/v3 (37.7MB) + att (12.6MB)
#define WS_XL    54919168ull                  // + Xb 4MB + Wb 288KB + Wob 96KB
#define QSCALE   0.25503486f                  // (1/sqrt(32)) * log2(e)

__device__ __forceinline__ float b2f(unsigned short u) {
    union { unsigned int i; float f; } v; v.i = ((unsigned int)u) << 16; return v.f;
}
__device__ __forceinline__ unsigned short f2b(float f) {
    union { float f; unsigned int i; } v; v.f = f;
    unsigned int x = v.i;
    return (unsigned short)((x + 0x7fffu + ((x >> 16) & 1u)) >> 16);
}
__device__ __forceinline__ unsigned int fbits(float f) {
    union { float f; unsigned int i; } v; v.f = f; return v.i;
}
__device__ __forceinline__ short8 cvt8(const float* p) {
    floatx4 a = *(const floatx4*)p;
    floatx4 b = *(const floatx4*)(p + 4);
    short8 r;
    r[0] = (short)f2b(a[0]); r[1] = (short)f2b(a[1]);
    r[2] = (short)f2b(a[2]); r[3] = (short)f2b(a[3]);
    r[4] = (short)f2b(b[0]); r[5] = (short)f2b(b[1]);
    r[6] = (short)f2b(b[2]); r[7] = (short)f2b(b[3]);
    return r;
}

// ---------------- K0: one-time f32->bf16 conversion of X, Wq/Wk/Wv, Wo --------
__global__ __launch_bounds__(256) void k_prep(
    const float* __restrict__ X,  const float* __restrict__ Wq,
    const float* __restrict__ Wk, const float* __restrict__ Wv,
    const float* __restrict__ Wo,
    unsigned short* __restrict__ Xb, unsigned short* __restrict__ Wb,
    unsigned short* __restrict__ Wob)
{
    size_t i = ((size_t)blockIdx.x * 256 + threadIdx.x) * 8;
    const float* src; unsigned short* dst; size_t off;
    if      (i < 2097152) { src = X;  dst = Xb;          off = i; }
    else if (i < 2146304) { src = Wq; dst = Wb;          off = i - 2097152; }
    else if (i < 2195456) { src = Wk; dst = Wb + 49152;  off = i - 2146304; }
    else if (i < 2244608) { src = Wv; dst = Wb + 98304;  off = i - 2195456; }
    else                  { src = Wo; dst = Wob;         off = i - 2244608; }
    *(short8*)&dst[off] = cvt8(&src[off]);
}

// ---------------- K1a: QKV projection, one (qkv,t) per block (R15) ------------
__global__ __launch_bounds__(256) void k_qkv_pre2(
    const unsigned short* __restrict__ Xb,   // [32][512][128] bf16
    const unsigned short* __restrict__ Wb,   // [3 qkv][3 t][128][128] bf16
    unsigned short* __restrict__ q_ws,
    unsigned short* __restrict__ k_ws,
    unsigned short* __restrict__ v_ws)
{
    int bp = blockIdx.x, mt = blockIdx.y, z = blockIdx.z;
    int qkv = z / 3, t = z % 3;
    __shared__ unsigned short Xs[128 * 128];     // 32 KB
    __shared__ unsigned short Cs[4][32 * 128];   // 32 KB (8KB per wave)
    int tid = threadIdx.x;
    int lane = tid & 63, wv = tid >> 6;
    int l15 = lane & 15, quad = lane >> 4;

    const unsigned short* Xbase = Xb + ((size_t)bp * 512 + mt * 128) * 128;
    for (int i = 0; i < 8; ++i) {
        int e = (i * 256 + tid) * 8;
        *(short8*)&Xs[e] = *(const short8*)&Xbase[e];
    }
    __syncthreads();

    unsigned short* Osel[3] = { q_ws, k_ws, v_ws };
    int rt0 = wv * 2, rt1 = wv * 2 + 1;

    const unsigned short* Wt = Wb + qkv * 49152 + t * 16384;
    unsigned short* Ob = Osel[qkv] + (size_t)t * 2097152
                       + ((size_t)bp * 512 + mt * 128 + wv * 32) * 128;
    float sc = (qkv == 0) ? QSCALE : 1.0f;

    for (int ct = 0; ct < 8; ++ct) {
        short8 bfr[4];
        for (int kk = 0; kk < 4; ++kk)
            bfr[kk] = *(const short8*)&Wt[(size_t)(ct * 16 + l15) * 128 + kk * 32 + quad * 8];
        floatx4 acc0 = {0.f, 0.f, 0.f, 0.f};
        floatx4 acc1 = {0.f, 0.f, 0.f, 0.f};
        for (int kk = 0; kk < 4; ++kk) {
            short8 a0 = *(const short8*)&Xs[(rt0 * 16 + l15) * 128 + kk * 32 + quad * 8];
            short8 a1 = *(const short8*)&Xs[(rt1 * 16 + l15) * 128 + kk * 32 + quad * 8];
            acc0 = __builtin_amdgcn_mfma_f32_16x16x32_bf16(a0, bfr[kk], acc0, 0, 0, 0);
            acc1 = __builtin_amdgcn_mfma_f32_16x16x32_bf16(a1, bfr[kk], acc1, 0, 0, 0);
        }
        #pragma unroll
        for (int i = 0; i < 4; ++i) {
            int row = quad * 4 + i;
            int swz = (row & 7) << 4;
            int col = (ct * 16 + l15) ^ swz;
            Cs[wv][row * 128 + col]        = f2b(acc0[i] * sc);
            Cs[wv][(16 + row) * 128 + col] = f2b(acc1[i] * sc);
        }
    }
    #pragma unroll
    for (int j = 0; j < 8; ++j) {
        int flat = j * 64 + lane;
        int r = flat >> 4;
        int cg = (flat & 15) * 8;
        int cgs = cg ^ ((r & 7) << 4);
        *(short8*)&Ob[(size_t)r * 128 + cg] = *(const short8*)&Cs[wv][r * 128 + cgs];
    }
}

// ---------------- K1b: QKV projection, inline-cvt fallback (unchanged) --------
__global__ __launch_bounds__(256) void k_qkv_cvt(
    const float* __restrict__ X,
    const float* __restrict__ Wq, const float* __restrict__ Wk,
    const float* __restrict__ Wv,
    unsigned short* __restrict__ q_ws, unsigned short* __restrict__ k_ws,
    unsigned short* __restrict__ v_ws,
    int wstride, int ostride)
{
    int bp = blockIdx.x, mt = blockIdx.y, tz = blockIdx.z;
    __shared__ unsigned short Xs[128 * 128];
    int tid = threadIdx.x;
    int lane = tid & 63, wv = tid >> 6;
    int l15 = lane & 15, quad = lane >> 4;

    const float* Xbase = X + ((size_t)bp * 512 + mt * 128) * 128;
    for (int i = 0; i < 8; ++i) {
        int e = (i * 256 + tid) * 8;
        *(short8*)&Xs[e] = cvt8(&Xbase[e]);
    }
    __syncthreads();

    size_t woff = (size_t)tz * wstride;
    size_t ooff = (size_t)tz * ostride;
    const float* Wsel[3] = { Wq + woff, Wk + woff, Wv + woff };
    unsigned short* Osel[3] = { q_ws + ooff, k_ws + ooff, v_ws + ooff };

    for (int qkv = 0; qkv < 3; ++qkv) {
        const float* Wt = Wsel[qkv];
        unsigned short* Ob = Osel[qkv] + ((size_t)bp * 512 + mt * 128) * 128;
        float sc = (qkv == 0) ? QSCALE : 1.0f;
        for (int ct = 0; ct < 8; ++ct) {
            short8 bfr[4];
            for (int kk = 0; kk < 4; ++kk)
                bfr[kk] = cvt8(&Wt[(size_t)(ct * 16 + l15) * 128 + kk * 32 + quad * 8]);
            floatx4 acc0 = {0.f, 0.f, 0.f, 0.f};
            floatx4 acc1 = {0.f, 0.f, 0.f, 0.f};
            int rt0 = wv * 2, rt1 = wv * 2 + 1;
            for (int kk = 0; kk < 4; ++kk) {
                short8 a0 = *(const short8*)&Xs[(rt0 * 16 + l15) * 128 + kk * 32 + quad * 8];
                short8 a1 = *(const short8*)&Xs[(rt1 * 16 + l15) * 128 + kk * 32 + quad * 8];
                acc0 = __builtin_amdgcn_mfma_f32_16x16x32_bf16(a0, bfr[kk], acc0, 0, 0, 0);
                acc1 = __builtin_amdgcn_mfma_f32_16x16x32_bf16(a1, bfr[kk], acc1, 0, 0, 0);
            }
            int col = ct * 16 + l15;
            for (int i = 0; i < 4; ++i) {
                Ob[(size_t)(rt0 * 16 + quad * 4 + i) * 128 + col] = f2b(acc0[i] * sc);
                Ob[(size_t)(rt1 * 16 + quad * 4 + i) * 128 + col] = f2b(acc1[i] * sc);
            }
        }
    }
}

// ---------------- K2: dense MFMA attention + depth-1 tm pipeline (R16) --------
// grid (nc2=2, bp=32, z=t*4+h) = 768 blocks. Same structure as proven k_attn2,
// but tm loads for body (c,s) are issued one body earlier into rotating
// register sets tmA/tmB (s=0 body prefetches (c,s=1); s=1 body prefetches
// (c+1,s=0)). Rolling base tpc advances 64 cols per c. c=7's forward prefetch
// reads in-slice memory (max row 383 < 512); values unused.
__global__ __launch_bounds__(512) void k_attn4(
    const unsigned short* __restrict__ q_ws,   // bf16, pre-scaled by QSCALE
    const unsigned short* __restrict__ k_ws,
    const unsigned short* __restrict__ v_ws,
    const float* __restrict__ tm,
    unsigned short* __restrict__ att_ws,       // [32][512][384] bf16
    int qkv_stride, int toff0)
{
    int nc2 = blockIdx.x;
    int bp = blockIdx.y;
    int z  = blockIdx.z;
    int t = z >> 2, h = z & 3;
    size_t qoff = (size_t)t * (size_t)qkv_stride;
    const float* tmt = tm + (size_t)(t + (t >> 1)) * 262144;
    int toff = toff0 + t * 128;

    __shared__ unsigned short Vt[32][516];
    __shared__ unsigned short Ps[8][16][72];

    int tid = threadIdx.x, lane = tid & 63, wv = tid >> 6;
    int l15 = lane & 15, quad = lane >> 4;

    {
        const unsigned short* vp = v_ws + qoff + ((size_t)bp * 512 + tid) * 128 + h * 32;
        short8 a = *(const short8*)vp;
        short8 b = *(const short8*)(vp + 8);
        short8 c = *(const short8*)(vp + 16);
        short8 d = *(const short8*)(vp + 24);
        #pragma unroll
        for (int j = 0; j < 8; ++j) {
            Vt[j][tid]      = (unsigned short)a[j];
            Vt[8 + j][tid]  = (unsigned short)b[j];
            Vt[16 + j][tid] = (unsigned short)c[j];
            Vt[24 + j][tid] = (unsigned short)d[j];
        }
    }
    int n0 = nc2 * 256 + wv * 16;              // strip 0; strip 1 at n0+128
    short8 qf[2];
    qf[0] = *(const short8*)&q_ws[qoff +
        ((size_t)bp * 512 + n0 + l15) * 128 + h * 32 + quad * 8];
    qf[1] = *(const short8*)&q_ws[qoff +
        ((size_t)bp * 512 + n0 + 128 + l15) * 128 + h * 32 + quad * 8];
    __syncthreads();

    const unsigned short* Kb = k_ws + qoff + (size_t)bp * 512 * 128 + h * 32;
    // per-lane tm base: row (n0 + s*128 + quad*4 + i), col (mb + ti*16 + l15)
    // tpc rolls forward 64 cols per c; offsets (s*128+i)*512 + ti*16 are
    // compile-time after s/i/ti unroll.
    const float* tpc = tmt + (size_t)(n0 + quad * 4) * 512 + l15;

    floatx4 O0[2] = {{0.f,0.f,0.f,0.f},{0.f,0.f,0.f,0.f}};
    floatx4 O1[2] = {{0.f,0.f,0.f,0.f},{0.f,0.f,0.f,0.f}};
    float za[2][4] = {{0.f,0.f,0.f,0.f},{0.f,0.f,0.f,0.f}};
    const floatx4 zero4 = {0.f, 0.f, 0.f, 0.f};

    float tmA[16], tmB[16];                    // [ti*4+i], rotating sets
    #pragma unroll
    for (int ti = 0; ti < 4; ++ti)
        #pragma unroll
        for (int i = 0; i < 4; ++i)
            tmA[ti * 4 + i] = tpc[i * 512 + ti * 16];   // (c=0, s=0)

    for (int c = 0; c < 8; ++c) {
        int mb = c * 64;
        short8 kf0 = *(const short8*)&Kb[(size_t)(mb +  0 + l15) * 128 + quad * 8];
        short8 kf1 = *(const short8*)&Kb[(size_t)(mb + 16 + l15) * 128 + quad * 8];
        short8 kf2 = *(const short8*)&Kb[(size_t)(mb + 32 + l15) * 128 + quad * 8];
        short8 kf3 = *(const short8*)&Kb[(size_t)(mb + 48 + l15) * 128 + quad * 8];

        // ================= s = 0 : prefetch (c, s=1) into tmB =================
        #pragma unroll
        for (int ti = 0; ti < 4; ++ti)
            #pragma unroll
            for (int i = 0; i < 4; ++i)
                tmB[ti * 4 + i] = tpc[(128 + i) * 512 + ti * 16];
        {
            floatx4 S[4];
            S[0] = __builtin_amdgcn_mfma_f32_16x16x32_bf16(qf[0], kf0, zero4, 0, 0, 0);
            S[1] = __builtin_amdgcn_mfma_f32_16x16x32_bf16(qf[0], kf1, zero4, 0, 0, 0);
            S[2] = __builtin_amdgcn_mfma_f32_16x16x32_bf16(qf[0], kf2, zero4, 0, 0, 0);
            S[3] = __builtin_amdgcn_mfma_f32_16x16x32_bf16(qf[0], kf3, zero4, 0, 0, 0);
            #pragma unroll
            for (int ti = 0; ti < 4; ++ti) {
                #pragma unroll
                for (int i = 0; i < 4; ++i) {
                    float tmv = tmA[ti * 4 + i];
                    float e = __builtin_amdgcn_exp2f(S[ti][i]);
                    za[0][i] += (tmv != 0.0f) ? e : 0.0f;
                    float w = e * tmv;                    // ==0 when masked
                    Ps[wv][quad * 4 + i][ti * 16 + l15] =
                        (unsigned short)((fbits(w) + 0x8000u) >> 16);  // half-up
                }
            }
            #pragma unroll
            for (int kc = 0; kc < 2; ++kc) {
                short8 pa  = *(const short8*)&Ps[wv][l15][kc * 32 + quad * 8];
                short8 vb0 = *(const short8*)&Vt[l15][mb + kc * 32 + quad * 8];
                short8 vb1 = *(const short8*)&Vt[16 + l15][mb + kc * 32 + quad * 8];
                O0[0] = __builtin_amdgcn_mfma_f32_16x16x32_bf16(pa, vb0, O0[0], 0, 0, 0);
                O1[0] = __builtin_amdgcn_mfma_f32_16x16x32_bf16(pa, vb1, O1[0], 0, 0, 0);
            }
        }

        // ================= s = 1 : prefetch (c+1, s=0) into tmA ===============
        #pragma unroll
        for (int ti = 0; ti < 4; ++ti)
            #pragma unroll
            for (int i = 0; i < 4; ++i)
                tmA[ti * 4 + i] = tpc[i * 512 + 64 + ti * 16];
        {
            floatx4 S[4];
            S[0] = __builtin_amdgcn_mfma_f32_16x16x32_bf16(qf[1], kf0, zero4, 0, 0, 0);
            S[1] = __builtin_amdgcn_mfma_f32_16x16x32_bf16(qf[1], kf1, zero4, 0, 0, 0);
            S[2] = __builtin_amdgcn_mfma_f32_16x16x32_bf16(qf[1], kf2, zero4, 0, 0, 0);
            S[3] = __builtin_amdgcn_mfma_f32_16x16x32_bf16(qf[1], kf3, zero4, 0, 0, 0);
            #pragma unroll
            for (int ti = 0; ti < 4; ++ti) {
                #pragma unroll
                for (int i = 0; i < 4; ++i) {
                    float tmv = tmB[ti * 4 + i];
                    float e = __builtin_amdgcn_exp2f(S[ti][i]);
                    za[1][i] += (tmv != 0.0f) ? e : 0.0f;
                    float w = e * tmv;
                    Ps[wv][quad * 4 + i][ti * 16 + l15] =
                        (unsigned short)((fbits(w) + 0x8000u) >> 16);
                }
            }
            #pragma unroll
            for (int kc = 0; kc < 2; ++kc) {
                short8 pa  = *(const short8*)&Ps[wv][l15][kc * 32 + quad * 8];
                short8 vb0 = *(const short8*)&Vt[l15][mb + kc * 32 + quad * 8];
                short8 vb1 = *(const short8*)&Vt[16 + l15][mb + kc * 32 + quad * 8];
                O0[1] = __builtin_amdgcn_mfma_f32_16x16x32_bf16(pa, vb0, O0[1], 0, 0, 0);
                O1[1] = __builtin_amdgcn_mfma_f32_16x16x32_bf16(pa, vb1, O1[1], 0, 0, 0);
            }
        }
        tpc += 64;
    }

    #pragma unroll
    for (int s = 0; s < 2; ++s) {
        #pragma unroll
        for (int d = 1; d < 16; d <<= 1) {
            #pragma unroll
            for (int i = 0; i < 4; ++i) za[s][i] += __shfl_xor(za[s][i], d, 64);
        }
        #pragma unroll
        for (int i = 0; i < 4; ++i) {
            float rz = 1.0f / za[s][i];
            size_t row = (size_t)bp * 512 + n0 + s * 128 + quad * 4 + i;
            att_ws[row * 384 + toff + h * 32 + l15]      = f2b(O0[s][i] * rz);
            att_ws[row * 384 + toff + h * 32 + 16 + l15] = f2b(O1[s][i] * rz);
        }
    }
}

// ---------------- K3a: out-projection, 32-row blocks + ct-split waves (R15) ---
__global__ __launch_bounds__(256) void k_oproj_pre2(
    const unsigned short* __restrict__ att_ws,   // [32][512][384] bf16
    const unsigned short* __restrict__ Wob,      // [128][384] bf16
    const float* __restrict__ X,
    const float* __restrict__ gamma,
    const float* __restrict__ beta,
    float* __restrict__ out)
{
    int bp = blockIdx.x;
    int mt = blockIdx.y;                         // 16 tiles of 32 rows
    __shared__ unsigned short As[32 * 128];      // 8 KB
    __shared__ unsigned short Ws[128 * 128];     // 32 KB
    __shared__ float Ls_s[2][32];                // per-ct-half row partials
    __shared__ float Ls_q[2][32];
    int tid = threadIdx.x, lane = tid & 63, wv = tid >> 6;
    int l15 = lane & 15, quad = lane >> 4;
    int rtile = wv & 1, chalf = wv >> 1;

    floatx4 acc[4];
    for (int ct = 0; ct < 4; ++ct) acc[ct] = (floatx4){0.f, 0.f, 0.f, 0.f};
    size_t rowbase = (size_t)bp * 512 + mt * 32;

    for (int kc = 0; kc < 3; ++kc) {
        __syncthreads();
        for (int i = 0; i < 2; ++i) {
            int flat = i * 256 + tid;
            int row = flat >> 4, colg = (flat & 15) * 8;
            *(short8*)&As[row * 128 + colg] =
                *(const short8*)&att_ws[(rowbase + row) * 384 + kc * 128 + colg];
        }
        for (int i = 0; i < 8; ++i) {
            int flat = i * 256 + tid;
            int row = flat >> 4, colg = (flat & 15) * 8;
            *(short8*)&Ws[row * 128 + colg] =
                *(const short8*)&Wob[(size_t)row * 384 + kc * 128 + colg];
        }
        __syncthreads();
        for (int ct = 0; ct < 4; ++ct) {
            for (int kk = 0; kk < 4; ++kk) {
                short8 a = *(const short8*)&As[(rtile * 16 + l15) * 128 + kk * 32 + quad * 8];
                short8 b = *(const short8*)&Ws[((chalf * 4 + ct) * 16 + l15) * 128 + kk * 32 + quad * 8];
                acc[ct] = __builtin_amdgcn_mfma_f32_16x16x32_bf16(a, b, acc[ct], 0, 0, 0);
            }
        }
    }

    float vals[4][4];                            // [i][ct], static indexing
    #pragma unroll
    for (int i = 0; i < 4; ++i) {
        int lrow = rtile * 16 + quad * 4 + i;
        size_t grow = rowbase + lrow;
        float s = 0.f, sq = 0.f;
        #pragma unroll
        for (int ct = 0; ct < 4; ++ct) {
            int col = (chalf * 4 + ct) * 16 + l15;
            float v = acc[ct][i] + X[grow * 128 + col];
            vals[i][ct] = v;
            s += v; sq += v * v;
        }
        #pragma unroll
        for (int d = 1; d < 16; d <<= 1) {
            s  += __shfl_xor(s, d, 64);
            sq += __shfl_xor(sq, d, 64);
        }
        if (l15 == 0) { Ls_s[chalf][lrow] = s; Ls_q[chalf][lrow] = sq; }
    }
    __syncthreads();
    #pragma unroll
    for (int i = 0; i < 4; ++i) {
        int lrow = rtile * 16 + quad * 4 + i;
        size_t grow = rowbase + lrow;
        float st  = Ls_s[0][lrow] + Ls_s[1][lrow];
        float sqt = Ls_q[0][lrow] + Ls_q[1][lrow];
        float mu = st * (1.0f / 128.0f);
        float var = sqt * (1.0f / 128.0f) - mu * mu;
        float rs = rsqrtf(var + 1e-5f);
        #pragma unroll
        for (int ct = 0; ct < 4; ++ct) {
            int col = (chalf * 4 + ct) * 16 + l15;
            out[grow * 128 + col] = (vals[i][ct] - mu) * rs * gamma[col] + beta[col];
        }
    }
}

// ---------------- K3b: out-projection, inline-cvt fallback (unchanged) --------
__global__ __launch_bounds__(256) void k_oproj_cvt(
    const unsigned short* __restrict__ att_ws,
    const float* __restrict__ Wo,
    const float* __restrict__ X,
    const float* __restrict__ gamma,
    const float* __restrict__ beta,
    float* __restrict__ out)
{
    int bp = blockIdx.x;
    int mt = blockIdx.y;
    __shared__ unsigned short As[64 * 128];
    __shared__ unsigned short Ws[128 * 128];
    int tid = threadIdx.x, lane = tid & 63, wv = tid >> 6;
    int l15 = lane & 15, quad = lane >> 4;

    floatx4 acc[8];
    for (int ct = 0; ct < 8; ++ct) acc[ct] = (floatx4){0.f, 0.f, 0.f, 0.f};
    size_t rowbase = (size_t)bp * 512 + mt * 64;

    for (int kc = 0; kc < 3; ++kc) {
        __syncthreads();
        for (int i = 0; i < 4; ++i) {
            int flat = i * 256 + tid;
            int row = flat >> 4, colg = (flat & 15) * 8;
            *(short8*)&As[row * 128 + colg] =
                *(const short8*)&att_ws[(rowbase + row) * 384 + kc * 128 + colg];
        }
        for (int i = 0; i < 8; ++i) {
            int flat = i * 256 + tid;
            int row = flat >> 4, colg = (flat & 15) * 8;
            *(short8*)&Ws[row * 128 + colg] = cvt8(&Wo[(size_t)row * 384 + kc * 128 + colg]);
        }
        __syncthreads();
        for (int ct = 0; ct < 8; ++ct) {
            for (int kk = 0; kk < 4; ++kk) {
                short8 a = *(const short8*)&As[(wv * 16 + l15) * 128 + kk * 32 + quad * 8];
                short8 b = *(const short8*)&Ws[(ct * 16 + l15) * 128 + kk * 32 + quad * 8];
                acc[ct] = __builtin_amdgcn_mfma_f32_16x16x32_bf16(a, b, acc[ct], 0, 0, 0);
            }
        }
    }

    for (int i = 0; i < 4; ++i) {
        int lrow = wv * 16 + quad * 4 + i;
        size_t grow = rowbase + lrow;
        float vals[8];
        float s = 0.f, sq = 0.f;
        for (int ct = 0; ct < 8; ++ct) {
            int col = ct * 16 + l15;
            float v = acc[ct][i] + X[grow * 128 + col];
            vals[ct] = v;
            s += v; sq += v * v;
        }
        for (int d = 1; d < 16; d <<= 1) {
            s  += __shfl_xor(s, d, 64);
            sq += __shfl_xor(sq, d, 64);
        }
        float mu = s * (1.0f / 128.0f);
        float var = sq * (1.0f / 128.0f) - mu * mu;
        float rs = rsqrtf(var + 1e-5f);
        for (int ct = 0; ct < 8; ++ct) {
            int col = ct * 16 + l15;
            out[grow * 128 + col] = (vals[ct] - mu) * rs * gamma[col] + beta[col];
        }
    }
}

// ---------------- launcher ----------------
extern "C" void kernel_launch(void* const* d_in, const int* in_sizes, int n_in,
                              void* d_out, int out_size, void* d_ws, size_t ws_size,
                              hipStream_t stream) {
    const float* X     = (const float*)d_in[0];
    const float* TM    = (const float*)d_in[2];
    const float* Wq    = (const float*)d_in[3];
    const float* Wk    = (const float*)d_in[4];
    const float* Wv    = (const float*)d_in[5];
    const float* Wo    = (const float*)d_in[6];
    const float* gamma = (const float*)d_in[7];
    const float* beta  = (const float*)d_in[8];
    float* out = (float*)d_out;

    char* ws = (char*)d_ws;
    const size_t QKV1 = 2097152;             // elems per t per tensor
    const size_t QKV1B = QKV1 * 2;           // 4 MB

    if (ws_size >= WS_XL) {
        unsigned short* q3  = (unsigned short*)(ws);
        unsigned short* k3  = (unsigned short*)(ws + 3 * QKV1B);
        unsigned short* v3  = (unsigned short*)(ws + 6 * QKV1B);
        unsigned short* att = (unsigned short*)(ws + 9 * QKV1B);
        unsigned short* Xb  = (unsigned short*)(ws + 50331648ull);
        unsigned short* Wb  = (unsigned short*)(ws + 54525952ull);
        unsigned short* Wob = (unsigned short*)(ws + 54820864ull);
        k_prep<<<dim3(1120), 256, 0, stream>>>(X, Wq, Wk, Wv, Wo, Xb, Wb, Wob);
        k_qkv_pre2<<<dim3(32, 4, 9), 256, 0, stream>>>(Xb, Wb, q3, k3, v3);
        k_attn4<<<dim3(2, 32, 12), 512, 0, stream>>>(q3, k3, v3, TM, att, (int)QKV1, 0);
        k_oproj_pre2<<<dim3(32, 16), 256, 0, stream>>>(att, Wob, X, gamma, beta, out);
    } else if (ws_size >= WS_BIG) {
        unsigned short* q3  = (unsigned short*)(ws);
        unsigned short* k3  = (unsigned short*)(ws + 3 * QKV1B);
        unsigned short* v3  = (unsigned short*)(ws + 6 * QKV1B);
        unsigned short* att = (unsigned short*)(ws + 9 * QKV1B);
        k_qkv_cvt<<<dim3(32, 4, 3), 256, 0, stream>>>(
            X, Wq, Wk, Wv, q3, k3, v3, 16384, (int)QKV1);
        k_attn4<<<dim3(2, 32, 12), 512, 0, stream>>>(q3, k3, v3, TM, att, (int)QKV1, 0);
        k_oproj_cvt<<<dim3(32, 8), 256, 0, stream>>>(att, Wo, X, gamma, beta, out);
    } else {
        unsigned short* q_ws   = (unsigned short*)(ws);
        unsigned short* k_ws   = (unsigned short*)(ws + QKV1B);
        unsigned short* v_ws   = (unsigned short*)(ws + 2 * QKV1B);
        unsigned short* att_ws = (unsigned short*)(ws + 3 * QKV1B);
        const int tsel[3] = {0, 1, 3};
        for (int t = 0; t < 3; ++t) {
            k_qkv_cvt<<<dim3(32, 4, 1), 256, 0, stream>>>(
                X, Wq + (size_t)t * 16384, Wk + (size_t)t * 16384, Wv + (size_t)t * 16384,
                q_ws, k_ws, v_ws, 0, 0);
            k_attn4<<<dim3(2, 32, 4), 512, 0, stream>>>(
                q_ws, k_ws, v_ws, TM + (size_t)tsel[t] * 262144, att_ws, 0, t * 128);
        }
        k_oproj_cvt<<<dim3(32, 8), 256, 0, stream>>>(att_ws, Wo, X, gamma, beta, out);
    }
}